// Round 4
// baseline (5897.677 us; speedup 1.0000x reference)
//
#include <hip/hip_runtime.h>
#include <math.h>

// ---------------- configuration ----------------
#define NHEAD 8
#define HID   768
#define FFND  3072
#define EOUTD 256
#define BATCH 1024
#define TOK   (BATCH*64)   // 65536

#define EPI_RESF  1
#define EPI_RESB  2
#define EPI_GELU  4
#define EPI_OUTF  8
#define EPI_OUTB  16

typedef __attribute__((ext_vector_type(8))) short short8;   // 8 x bf16
typedef __attribute__((ext_vector_type(4))) float f32x4;    // MFMA C/D

#define AS1 __attribute__((address_space(1)))
#define AS3 __attribute__((address_space(3)))

__device__ __forceinline__ void async16(const void* g, void* l) {
  __builtin_amdgcn_global_load_lds(
      (AS1 unsigned int*)(unsigned long long)g,
      (AS3 unsigned int*)(unsigned int)(unsigned long long)l,
      16, 0, 0);
}

__device__ __forceinline__ float bf2f(unsigned short u) {
  union { unsigned int i; float f; } c; c.i = ((unsigned int)u) << 16; return c.f;
}
__device__ __forceinline__ unsigned short f2bf(float f) {
  union { float f; unsigned int i; } c; c.f = f;
  unsigned int x = c.i + 0x7fffu + ((c.i >> 16) & 1u);   // RNE
  return (unsigned short)(x >> 16);
}
__device__ __forceinline__ float wsum(float v) {
#pragma unroll
  for (int o = 32; o > 0; o >>= 1) v += __shfl_xor(v, o);
  return v;
}
// GELU with fast erf (Abramowitz-Stegun 7.1.26, |err| < 1.5e-7)
__device__ __forceinline__ float gelu_f(float v) {
  const float z = fabsf(v) * 0.70710678118654752f;
  const float t = 1.0f / (1.0f + 0.3275911f * z);
  const float poly = t * (0.254829592f + t * (-0.284496736f +
                     t * (1.421413741f + t * (-1.453152027f + t * 1.061405429f))));
  float erfv = 1.0f - poly * __expf(-z * z);
  erfv = (v < 0.f) ? -erfv : erfv;
  return 0.5f * v * (1.0f + erfv);
}

// ---------------- register-streaming GEMM (barrier-free, LDS-free) ----------------
// C[M,N] = A[M,K] @ Wt[N,K]^T. One block = 64 rows of A; 8 waves; each wave
// computes 64x48 per n-step (n-steps of 384). A-frags and B-frags are loaded
// DIRECTLY from global (B is a small L2-resident weight panel shared by all
// blocks; A's 4KB k-slice is shared by the 8 waves via L1). No __syncthreads,
// no LDS: the compiler pipelines loads against MFMA with fine-grained vmcnt.
// Requires: M % 64 == 0, N % 384 == 0, K % 32 == 0.
template<int EPI>
__global__ __launch_bounds__(512, 3) void rgemm_k(
    const unsigned short* __restrict__ A, const unsigned short* __restrict__ Wt,
    const float* __restrict__ bias,
    const float* __restrict__ residF, const unsigned short* __restrict__ residB,
    float* __restrict__ outF, unsigned short* __restrict__ outB,
    int N, int K)
{
  const int tid  = threadIdx.x;
  const int wv   = tid >> 6;          // 0..7
  const int lane = tid & 63;
  const int c    = lane & 15, quad = lane >> 4;
  const int m0   = blockIdx.x * 64;

  const unsigned short* aBase = A + (long)(m0 + c) * K + quad * 8;

  for (int n0 = wv * 48; n0 < N; n0 += 384) {
    const unsigned short* bBase = Wt + (long)(n0 + c) * K + quad * 8;

    f32x4 zero = {0.f, 0.f, 0.f, 0.f};
    f32x4 acc[4][3];
#pragma unroll
    for (int i = 0; i < 4; i++)
#pragma unroll
      for (int j = 0; j < 3; j++) acc[i][j] = zero;

    for (int k0 = 0; k0 < K; k0 += 32) {
      short8 af[4], bfr[3];
#pragma unroll
      for (int mi = 0; mi < 4; mi++)
        af[mi] = *(const short8*)(aBase + (long)mi * 16 * K + k0);
#pragma unroll
      for (int ci = 0; ci < 3; ci++)
        bfr[ci] = *(const short8*)(bBase + (long)ci * 16 * K + k0);
#pragma unroll
      for (int mi = 0; mi < 4; mi++)
#pragma unroll
        for (int ci = 0; ci < 3; ci++)
          acc[mi][ci] = __builtin_amdgcn_mfma_f32_16x16x32_bf16(af[mi], bfr[ci], acc[mi][ci], 0, 0, 0);
    }

    // epilogue: C/D layout col = lane&15, row = quad*4 + r  [verified m89/m91]
#pragma unroll
    for (int mi = 0; mi < 4; mi++) {
#pragma unroll
      for (int r = 0; r < 4; r++) {
        const int row = m0 + mi * 16 + quad * 4 + r;
        const long rb = (long)row * N;
#pragma unroll
        for (int ci = 0; ci < 3; ci++) {
          const int col = n0 + ci * 16 + c;
          float v = acc[mi][ci][r] + bias[col];
          if (EPI & EPI_RESF) v += residF[rb + col];
          if (EPI & EPI_RESB) v += bf2f(residB[rb + col]);
          if (EPI & EPI_GELU) v = gelu_f(v);
          if (EPI & EPI_OUTF) outF[rb + col] = v;
          if (EPI & EPI_OUTB) outB[rb + col] = f2bf(v);
        }
      }
    }
  }
}

// ---------------- LDS-staged GEMM (kept for the two tiny pool GEMMs) ----------------
// 128x128 tile, BK=64, global_load_lds width-16, XOR-swizzled k-chunks.
template<int EPI>
__global__ __launch_bounds__(256) void gemm_k(
    const unsigned short* __restrict__ A, const unsigned short* __restrict__ Wt,
    const float* __restrict__ bias,
    const float* __restrict__ residF, const unsigned short* __restrict__ residB,
    float* __restrict__ outF, unsigned short* __restrict__ outB,
    int M, int N, int K)
{
  __shared__ unsigned short lA[128 * 64];
  __shared__ unsigned short lB[128 * 64];
  const int tid  = threadIdx.x;
  const int n0   = blockIdx.x * 128;
  const int m0   = blockIdx.y * 128;
  const int lane = tid & 63;
  const int wid  = tid >> 6;
  const int wm   = wid & 1, wn = wid >> 1;
  const int m16  = lane & 15, quad = lane >> 4;

  f32x4 zero = {0.0f, 0.0f, 0.0f, 0.0f};
  f32x4 acc[4][4];
#pragma unroll
  for (int i = 0; i < 4; i++)
#pragma unroll
    for (int j = 0; j < 4; j++) acc[i][j] = zero;

  long aoff[4], boff[4];
#pragma unroll
  for (int j = 0; j < 4; j++) {
    const int L = tid + j * 256;
    const int row = L >> 3;
    const int kc  = (L & 7) ^ (row & 7);
    aoff[j] = (long)(m0 + row) * K + kc * 8;
    boff[j] = (long)(n0 + row) * K + kc * 8;
  }

  for (int k0 = 0; k0 < K; k0 += 64) {
#pragma unroll
    for (int j = 0; j < 4; j++)
      async16(A + aoff[j] + k0, lA + (size_t)(j * 256 + wid * 64) * 8);
#pragma unroll
    for (int j = 0; j < 4; j++)
      async16(Wt + boff[j] + k0, lB + (size_t)(j * 256 + wid * 64) * 8);
    __syncthreads();
#pragma unroll
    for (int s = 0; s < 2; s++) {
      short8 af[4], bfr[4];
#pragma unroll
      for (int mi = 0; mi < 4; mi++) {
        const int row = wm * 64 + mi * 16 + m16;
        const int kc  = (s * 4 + quad) ^ (row & 7);
        af[mi] = *(const short8*)(lA + row * 64 + kc * 8);
      }
#pragma unroll
      for (int ni = 0; ni < 4; ni++) {
        const int row = wn * 64 + ni * 16 + m16;
        const int kc  = (s * 4 + quad) ^ (row & 7);
        bfr[ni] = *(const short8*)(lB + row * 64 + kc * 8);
      }
#pragma unroll
      for (int mi = 0; mi < 4; mi++)
#pragma unroll
        for (int ni = 0; ni < 4; ni++)
          acc[mi][ni] = __builtin_amdgcn_mfma_f32_16x16x32_bf16(af[mi], bfr[ni], acc[mi][ni], 0, 0, 0);
    }
    __syncthreads();
  }

#pragma unroll
  for (int mi = 0; mi < 4; mi++) {
#pragma unroll
    for (int r = 0; r < 4; r++) {
      const int row = m0 + wm * 64 + mi * 16 + quad * 4 + r;
      const long rb = (long)row * N;
#pragma unroll
      for (int ni = 0; ni < 4; ni++) {
        const int col = n0 + wn * 64 + ni * 16 + m16;
        float v = acc[mi][ni][r] + bias[col];
        if (EPI & EPI_RESF) v += residF[rb + col];
        if (EPI & EPI_RESB) v += bf2f(residB[rb + col]);
        if (EPI & EPI_GELU) v = gelu_f(v);
        if (EPI & EPI_OUTF) outF[rb + col] = v;
        if (EPI & EPI_OUTB) outB[rb + col] = f2bf(v);
      }
    }
  }
}

// ---------------- Fastformer attention / pooling: MFMA Gram-matrix version ----------------
template<bool POOL>
__global__ __launch_bounds__(256) void fastattn2_k(
    const unsigned short* __restrict__ Q,
    const unsigned short* __restrict__ Kx,
    const unsigned short* __restrict__ V,
    int ld,
    const int* __restrict__ mask,
    unsigned short* __restrict__ attnO,
    unsigned short* __restrict__ fused,
    float* __restrict__ qres)
{
  const int lane = threadIdx.x & 63;
  const int wid  = threadIdx.x >> 6;
  const int gw   = blockIdx.x * 4 + wid;
  const int b = gw >> 3, h = gw & 7;
  const int c = lane & 15, quad = lane >> 4;
  const unsigned short* Qp = Q  + (long)b * 64 * ld + h * 96;
  const unsigned short* Kp = Kx + (long)b * 64 * ld + h * 96;
  const unsigned short* Vp = V  + (long)b * 64 * ld + h * 96;
  const float mval = (mask[b * 64 + lane] != 0) ? 1.0f : 0.0f;

  f32x4 G[4][4];
  f32x4 zero = {0.f, 0.f, 0.f, 0.f};
#pragma unroll
  for (int mi = 0; mi < 4; mi++)
#pragma unroll
    for (int ni = 0; ni < 4; ni++) G[mi][ni] = zero;
  float ql[4] = {0.f, 0.f, 0.f, 0.f};

#pragma unroll
  for (int kc = 0; kc < 3; kc++) {
    const int dcol = kc * 32 + quad * 8;
    short8 afr[4], bfr[4];
#pragma unroll
    for (int mi = 0; mi < 4; mi++)
      afr[mi] = *(const short8*)(Kp + (long)(mi * 16 + c) * ld + dcol);
#pragma unroll
    for (int ni = 0; ni < 4; ni++)
      bfr[ni] = *(const short8*)(Qp + (long)(ni * 16 + c) * ld + dcol);
#pragma unroll
    for (int ni = 0; ni < 4; ni++) {
      float t = 0.f;
#pragma unroll
      for (int j = 0; j < 8; j++) t += bf2f((unsigned short)bfr[ni][j]);
      ql[ni] += t;
    }
#pragma unroll
    for (int mi = 0; mi < 4; mi++)
#pragma unroll
      for (int ni = 0; ni < 4; ni++)
        G[mi][ni] = __builtin_amdgcn_mfma_f32_16x16x32_bf16(afr[mi], bfr[ni], G[mi][ni], 0, 0, 0);
  }
#pragma unroll
  for (int ni = 0; ni < 4; ni++) {
    ql[ni] += __shfl_xor(ql[ni], 16);
    ql[ni] += __shfl_xor(ql[ni], 32);
  }

  float qw[4];
  {
    float lg[4], mx = -3.4e38f;
#pragma unroll
    for (int ni = 0; ni < 4; ni++) {
      const float mk = __shfl(mval, ni * 16 + c);
      lg[ni] = (mk > 0.5f) ? ql[ni] * 0.102062072615966f : -10000.0f;
      mx = fmaxf(mx, lg[ni]);
    }
#pragma unroll
    for (int o = 1; o <= 8; o <<= 1) mx = fmaxf(mx, __shfl_xor(mx, o));
    float se = 0.f;
#pragma unroll
    for (int ni = 0; ni < 4; ni++) { qw[ni] = expf(lg[ni] - mx); se += qw[ni]; }
#pragma unroll
    for (int o = 1; o <= 8; o <<= 1) se += __shfl_xor(se, o);
    const float inv = 1.0f / se;
#pragma unroll
    for (int ni = 0; ni < 4; ni++) qw[ni] *= inv;
  }

  float kw[16];
#pragma unroll
  for (int mi = 0; mi < 4; mi++)
#pragma unroll
    for (int r = 0; r < 4; r++) {
      float a = 0.f;
#pragma unroll
      for (int ni = 0; ni < 4; ni++) a += G[mi][ni][r] * qw[ni];
      kw[mi * 4 + r] = a;
    }
#pragma unroll
  for (int i = 0; i < 16; i++)
#pragma unroll
    for (int o = 1; o <= 8; o <<= 1) kw[i] += __shfl_xor(kw[i], o);

  {
    float mx2 = -3.4e38f;
#pragma unroll
    for (int i = 0; i < 16; i++) {
      const int mi = i >> 2, r = i & 3;
      const float mk = __shfl(mval, mi * 16 + quad * 4 + r);
      kw[i] = (mk > 0.5f) ? kw[i] : -10000.0f;
      mx2 = fmaxf(mx2, kw[i]);
    }
    mx2 = fmaxf(mx2, __shfl_xor(mx2, 16));
    mx2 = fmaxf(mx2, __shfl_xor(mx2, 32));
    float se2 = 0.f;
#pragma unroll
    for (int i = 0; i < 16; i++) { kw[i] = expf(kw[i] - mx2); se2 += kw[i]; }
    se2 += __shfl_xor(se2, 16);
    se2 += __shfl_xor(se2, 32);
    const float inv = 1.0f / se2;
#pragma unroll
    for (int i = 0; i < 16; i++) kw[i] *= inv;
  }

  float vw[4];
  {
    float vl[4] = {0.f, 0.f, 0.f, 0.f};
#pragma unroll
    for (int ni = 0; ni < 4; ni++) {
#pragma unroll
      for (int mi = 0; mi < 4; mi++)
#pragma unroll
        for (int r = 0; r < 4; r++) vl[ni] += G[mi][ni][r] * kw[mi * 4 + r];
      vl[ni] += __shfl_xor(vl[ni], 16);
      vl[ni] += __shfl_xor(vl[ni], 32);
    }
    float mx = -3.4e38f;
#pragma unroll
    for (int ni = 0; ni < 4; ni++) {
      const float mk = __shfl(mval, ni * 16 + c);
      vl[ni] = (mk > 0.5f) ? vl[ni] : -10000.0f;
      mx = fmaxf(mx, vl[ni]);
    }
#pragma unroll
    for (int o = 1; o <= 8; o <<= 1) mx = fmaxf(mx, __shfl_xor(mx, o));
    float se = 0.f;
#pragma unroll
    for (int ni = 0; ni < 4; ni++) { vw[ni] = expf(vl[ni] - mx); se += vw[ni]; }
#pragma unroll
    for (int o = 1; o <= 8; o <<= 1) se += __shfl_xor(se, o);
    const float inv = 1.0f / se;
#pragma unroll
    for (int ni = 0; ni < 4; ni++) vw[ni] *= inv;
  }

  if (!POOL) {
    __shared__ float swv[4][64];
    if (quad == 0) {
#pragma unroll
      for (int ni = 0; ni < 4; ni++) swv[wid][ni * 16 + c] = vw[ni];
    }
    __syncthreads();
    unsigned short* Op = attnO + (long)b * 64 * 768 + h * 96;
#pragma unroll
    for (int it = 0; it < 12; it++) {
      const int idx = it * 64 + lane;
      const int s = idx / 12, cw = idx % 12;
      short8 v = *(const short8*)(Vp + (long)s * ld + cw * 8);
      const float w = swv[wid][s];
      short8 o;
#pragma unroll
      for (int j = 0; j < 8; j++) o[j] = (short)f2bf(w * bf2f((unsigned short)v[j]));
      *(short8*)(Op + (long)s * 768 + cw * 8) = o;
    }
  } else {
    float qg[24], vg[24];
#pragma unroll
    for (int kc = 0; kc < 3; kc++) {
      const int dcol = kc * 32 + quad * 8;
      short8 fq[4], fv[4];
#pragma unroll
      for (int ni = 0; ni < 4; ni++) {
        fq[ni] = *(const short8*)(Qp + (long)(ni * 16 + c) * ld + dcol);
        fv[ni] = *(const short8*)(Vp + (long)(ni * 16 + c) * ld + dcol);
      }
#pragma unroll
      for (int j = 0; j < 8; j++) {
        float aq = 0.f, av = 0.f;
#pragma unroll
        for (int ni = 0; ni < 4; ni++) {
          aq += qw[ni] * bf2f((unsigned short)fq[ni][j]);
          av += vw[ni] * bf2f((unsigned short)fv[ni][j]);
        }
        qg[kc * 8 + j] = aq; vg[kc * 8 + j] = av;
      }
    }
#pragma unroll
    for (int i = 0; i < 24; i++) {
#pragma unroll
      for (int o = 1; o <= 8; o <<= 1) {
        qg[i] += __shfl_xor(qg[i], o);
        vg[i] += __shfl_xor(vg[i], o);
      }
    }
    if (c == 0) {
#pragma unroll
      for (int kc = 0; kc < 3; kc++)
#pragma unroll
        for (int j = 0; j < 8; j++) {
          const int d = kc * 32 + quad * 8 + j;
          const float qv = qg[kc * 8 + j], vv = vg[kc * 8 + j];
          fused[(long)b * 1536 + d * 8 + h]        = f2bf(qv);
          fused[(long)b * 1536 + (96 + d) * 8 + h] = f2bf(vv);
          qres[(long)b * 768 + d * 8 + h] = qv;
        }
    }
  }
}

// ---------------- LayerNorms ----------------
__global__ __launch_bounds__(256) void ln768_k(
    const float* __restrict__ x, const float* __restrict__ g, const float* __restrict__ b,
    unsigned short* __restrict__ out)
{
  const int tid = threadIdx.x;
  const long row = blockIdx.x;
  const float* xr = x + row * 768;
  const float v0 = xr[tid], v1 = xr[tid + 256], v2 = xr[tid + 512];
  __shared__ float red[4];
  const int wid = tid >> 6, ln = tid & 63;
  float s = wsum(v0 + v1 + v2);
  if (ln == 0) red[wid] = s;
  __syncthreads();
  const float mean = (red[0] + red[1] + red[2] + red[3]) * (1.0f / 768.0f);
  __syncthreads();
  const float d0 = v0 - mean, d1 = v1 - mean, d2 = v2 - mean;
  float q = wsum(d0 * d0 + d1 * d1 + d2 * d2);
  if (ln == 0) red[wid] = q;
  __syncthreads();
  const float var = (red[0] + red[1] + red[2] + red[3]) * (1.0f / 768.0f);
  const float rs = rsqrtf(var + 1e-5f);
  unsigned short* o = out + row * 768;
  o[tid]       = f2bf(d0 * rs * g[tid]       + b[tid]);
  o[tid + 256] = f2bf(d1 * rs * g[tid + 256] + b[tid + 256]);
  o[tid + 512] = f2bf(d2 * rs * g[tid + 512] + b[tid + 512]);
}

__global__ __launch_bounds__(256) void ln768b_k(
    const unsigned short* __restrict__ x, const float* __restrict__ g, const float* __restrict__ b,
    unsigned short* __restrict__ out)
{
  const int tid = threadIdx.x;
  const long row = blockIdx.x;
  const unsigned short* xr = x + row * 768;
  const float v0 = bf2f(xr[tid]), v1 = bf2f(xr[tid + 256]), v2 = bf2f(xr[tid + 512]);
  __shared__ float red[4];
  const int wid = tid >> 6, ln = tid & 63;
  float s = wsum(v0 + v1 + v2);
  if (ln == 0) red[wid] = s;
  __syncthreads();
  const float mean = (red[0] + red[1] + red[2] + red[3]) * (1.0f / 768.0f);
  __syncthreads();
  const float d0 = v0 - mean, d1 = v1 - mean, d2 = v2 - mean;
  float q = wsum(d0 * d0 + d1 * d1 + d2 * d2);
  if (ln == 0) red[wid] = q;
  __syncthreads();
  const float var = (red[0] + red[1] + red[2] + red[3]) * (1.0f / 768.0f);
  const float rs = rsqrtf(var + 1e-5f);
  unsigned short* o = out + row * 768;
  o[tid]       = f2bf(d0 * rs * g[tid]       + b[tid]);
  o[tid + 256] = f2bf(d1 * rs * g[tid + 256] + b[tid + 256]);
  o[tid + 512] = f2bf(d2 * rs * g[tid + 512] + b[tid + 512]);
}

__global__ __launch_bounds__(256) void ln2x_k(
    const float* __restrict__ x,
    const float* __restrict__ g1, const float* __restrict__ b1,
    const float* __restrict__ g2, const float* __restrict__ b2,
    unsigned short* __restrict__ out)
{
  const int tid = threadIdx.x;
  const long row = blockIdx.x;
  const float* xr = x + row * 768;
  const float v0 = xr[tid], v1 = xr[tid + 256], v2 = xr[tid + 512];
  __shared__ float red[4];
  const int wid = tid >> 6, ln = tid & 63;
  float s = wsum(v0 + v1 + v2);
  if (ln == 0) red[wid] = s;
  __syncthreads();
  const float mean = (red[0] + red[1] + red[2] + red[3]) * (1.0f / 768.0f);
  __syncthreads();
  const float d0 = v0 - mean, d1 = v1 - mean, d2 = v2 - mean;
  float q = wsum(d0 * d0 + d1 * d1 + d2 * d2);
  if (ln == 0) red[wid] = q;
  __syncthreads();
  const float var = (red[0] + red[1] + red[2] + red[3]) * (1.0f / 768.0f);
  const float rs = rsqrtf(var + 1e-5f);
  const float y0 = d0 * rs * g1[tid]       + b1[tid];
  const float y1 = d1 * rs * g1[tid + 256] + b1[tid + 256];
  const float y2 = d2 * rs * g1[tid + 512] + b1[tid + 512];
  __syncthreads();
  float s2 = wsum(y0 + y1 + y2);
  if (ln == 0) red[wid] = s2;
  __syncthreads();
  const float mean2 = (red[0] + red[1] + red[2] + red[3]) * (1.0f / 768.0f);
  __syncthreads();
  const float e0 = y0 - mean2, e1 = y1 - mean2, e2 = y2 - mean2;
  float q2 = wsum(e0 * e0 + e1 * e1 + e2 * e2);
  if (ln == 0) red[wid] = q2;
  __syncthreads();
  const float var2 = (red[0] + red[1] + red[2] + red[3]) * (1.0f / 768.0f);
  const float rs2 = rsqrtf(var2 + 1e-5f);
  unsigned short* o = out + row * 768;
  o[tid]       = f2bf(e0 * rs2 * g2[tid]       + b2[tid]);
  o[tid + 256] = f2bf(e1 * rs2 * g2[tid + 256] + b2[tid + 256]);
  o[tid + 512] = f2bf(e2 * rs2 * g2[tid + 512] + b2[tid + 512]);
}

__global__ __launch_bounds__(256) void lnf_k(
    const float* __restrict__ x, const float* __restrict__ g, const float* __restrict__ b,
    float* __restrict__ out)
{
  const int tid = threadIdx.x;
  const long row = blockIdx.x;
  const float v = x[row * 256 + tid];
  __shared__ float red[4];
  const int wid = tid >> 6, ln = tid & 63;
  float s = wsum(v);
  if (ln == 0) red[wid] = s;
  __syncthreads();
  const float mean = (red[0] + red[1] + red[2] + red[3]) * (1.0f / 256.0f);
  __syncthreads();
  const float d = v - mean;
  float q = wsum(d * d);
  if (ln == 0) red[wid] = q;
  __syncthreads();
  const float var = (red[0] + red[1] + red[2] + red[3]) * (1.0f / 256.0f);
  const float rs = rsqrtf(var + 1e-5f);
  out[row * 256 + tid] = d * rs * g[tid] + b[tid];
}

// ---------------- weight transpose + cast, bias concat ----------------
__global__ __launch_bounds__(256) void tcast_k(
    const float* __restrict__ W, unsigned short* __restrict__ Wt, int K, int N)
{
  __shared__ float t[32][33];
  const int tx = threadIdx.x & 31, ty = threadIdx.x >> 5;
  const int n0 = blockIdx.x * 32, k0 = blockIdx.y * 32;
#pragma unroll
  for (int j = 0; j < 32; j += 8)
    t[ty + j][tx] = W[(long)(k0 + ty + j) * N + n0 + tx];
  __syncthreads();
#pragma unroll
  for (int j = 0; j < 32; j += 8)
    Wt[(long)(n0 + ty + j) * K + k0 + tx] = f2bf(t[tx][ty + j]);
}

__global__ __launch_bounds__(256) void cat3_k(
    const float* __restrict__ a, const float* __restrict__ b, const float* __restrict__ c,
    float* __restrict__ dst)
{
  const int i = blockIdx.x * 256 + threadIdx.x;   // grid 9 -> 2304
  dst[i] = (i < 768) ? a[i] : (i < 1536 ? b[i - 768] : c[i - 1536]);
}

// ---------------- launcher ----------------
extern "C" void kernel_launch(void* const* d_in, const int* in_sizes, int n_in,
                              void* d_out, int out_size, void* d_ws, size_t ws_size,
                              hipStream_t stream)
{
  const float* x    = (const float*)d_in[0];
  const int*   mask = (const int*)d_in[1];
  const float* n1g = (const float*)d_in[2];  const float* n1b = (const float*)d_in[3];
  const float* wq  = (const float*)d_in[4];  const float* bq  = (const float*)d_in[5];
  const float* wk  = (const float*)d_in[6];  const float* bk  = (const float*)d_in[7];
  const float* wv  = (const float*)d_in[8];  const float* bv  = (const float*)d_in[9];
  const float* wo  = (const float*)d_in[10]; const float* bo  = (const float*)d_in[11];
  const float* n2g = (const float*)d_in[12]; const float* n2b = (const float*)d_in[13];
  const float* w1  = (const float*)d_in[14]; const float* b1  = (const float*)d_in[15];
  const float* w2  = (const float*)d_in[16]; const float* b2  = (const float*)d_in[17];
  const float* pwq = (const float*)d_in[18]; const float* pbq = (const float*)d_in[19];
  const float* pwk = (const float*)d_in[20]; const float* pbk = (const float*)d_in[21];
  const float* pwv = (const float*)d_in[22]; const float* pbv = (const float*)d_in[23];
  const float* pwo = (const float*)d_in[24]; const float* pbo = (const float*)d_in[25];
  const float* png = (const float*)d_in[26]; const float* pnb = (const float*)d_in[27];
  const float* tng = (const float*)d_in[28]; const float* tnb = (const float*)d_in[29];
  const float* pjw = (const float*)d_in[30]; const float* pjb = (const float*)d_in[31];
  const float* ong = (const float*)d_in[32]; const float* onb = (const float*)d_in[33];
  float* out = (float*)d_out;

  char* p = (char*)d_ws;
  auto alloc = [&](size_t n) { void* r = (void*)p; p += (n + 255) & ~(size_t)255; return r; };

  unsigned short* wqkvt = (unsigned short*)alloc((size_t)3 * HID * HID * 2);  // 2304 x 768
  unsigned short* wot   = (unsigned short*)alloc((size_t)HID * HID * 2);
  unsigned short* w1t   = (unsigned short*)alloc((size_t)FFND * HID * 2);
  unsigned short* w2t   = (unsigned short*)alloc((size_t)HID * FFND * 2);
  unsigned short* pqkvt = (unsigned short*)alloc((size_t)3 * HID * HID * 2);
  unsigned short* pwot  = (unsigned short*)alloc((size_t)HID * 2 * HID * 2);
  unsigned short* pjwt  = (unsigned short*)alloc((size_t)EOUTD * HID * 2);
  float*          qkvbias = (float*)alloc((size_t)3 * HID * 4);
  float*          pqkvbias= (float*)alloc((size_t)3 * HID * 4);
  unsigned short* bfA   = (unsigned short*)alloc((size_t)TOK * HID * 2);      // h1 -> h -> x3
  unsigned short* QKVb  = (unsigned short*)alloc((size_t)TOK * 3 * HID * 2);  // 65536 x 2304
  unsigned short* bfB   = (unsigned short*)alloc((size_t)TOK * HID * 2);      // attn -> ffn-hidden chunk
  unsigned short* x2b   = (unsigned short*)alloc((size_t)TOK * HID * 2);      // x2 (bf16)
  unsigned short* fusedb= (unsigned short*)alloc((size_t)BATCH * 2 * HID * 2);
  float*          qresb = (float*)alloc((size_t)BATCH * HID * 4);
  float*          preln = (float*)alloc((size_t)BATCH * HID * 4);
  unsigned short* pooledb=(unsigned short*)alloc((size_t)BATCH * HID * 2);
  float*          news  = (float*)alloc((size_t)BATCH * EOUTD * 4);
  (void)ws_size; (void)in_sizes; (void)n_in; (void)out_size;

  // weight prep
  tcast_k<<<dim3(HID/32,  HID/32),  256, 0, stream>>>(wq,  wqkvt,                 HID, HID);
  tcast_k<<<dim3(HID/32,  HID/32),  256, 0, stream>>>(wk,  wqkvt + (size_t)HID*HID,   HID, HID);
  tcast_k<<<dim3(HID/32,  HID/32),  256, 0, stream>>>(wv,  wqkvt + (size_t)2*HID*HID, HID, HID);
  tcast_k<<<dim3(HID/32,  HID/32),  256, 0, stream>>>(wo,  wot,  HID,  HID);
  tcast_k<<<dim3(FFND/32, HID/32),  256, 0, stream>>>(w1,  w1t,  HID,  FFND);
  tcast_k<<<dim3(HID/32,  FFND/32), 256, 0, stream>>>(w2,  w2t,  FFND, HID);
  tcast_k<<<dim3(HID/32,  HID/32),  256, 0, stream>>>(pwq, pqkvt,                 HID, HID);
  tcast_k<<<dim3(HID/32,  HID/32),  256, 0, stream>>>(pwk, pqkvt + (size_t)HID*HID,   HID, HID);
  tcast_k<<<dim3(HID/32,  HID/32),  256, 0, stream>>>(pwv, pqkvt + (size_t)2*HID*HID, HID, HID);
  tcast_k<<<dim3(HID/32,  (2*HID)/32), 256, 0, stream>>>(pwo, pwot, 2*HID, HID);
  tcast_k<<<dim3(EOUTD/32, HID/32), 256, 0, stream>>>(pjw, pjwt, HID,  EOUTD);
  cat3_k<<<9, 256, 0, stream>>>(bq,  bk,  bv,  qkvbias);
  cat3_k<<<9, 256, 0, stream>>>(pbq, pbk, pbv, pqkvbias);

  // LN1
  ln768_k<<<TOK, 256, 0, stream>>>(x, n1g, n1b, bfA);

  // fused QKV GEMM: 65536 x 2304, K=768 (register-streaming)
  rgemm_k<EPI_OUTB><<<TOK/64, 512, 0, stream>>>(
      bfA, wqkvt, qkvbias, nullptr, nullptr, nullptr, QKVb, 3*HID, HID);

  // fastformer attention -> bfB (stride 768)
  fastattn2_k<false><<<BATCH * NHEAD / 4, 256, 0, stream>>>(
      QKVb, QKVb + HID, QKVb + 2*HID, 3*HID, mask, bfB, nullptr, nullptr);

  // wo proj + f32 resid x -> x2 (bf16)
  rgemm_k<EPI_OUTB | EPI_RESF><<<TOK/64, 512, 0, stream>>>(
      bfB, wot, bo, x, nullptr, nullptr, x2b, HID, HID);

  // LN2 (bf16 in)
  ln768b_k<<<TOK, 256, 0, stream>>>(x2b, n2g, n2b, bfA);

  // FFN in 4 row-chunks of 16384 (hidden reuses bfB)
  for (int c = 0; c < 4; c++) {
    const size_t ro = (size_t)c * 16384;
    rgemm_k<EPI_OUTB | EPI_GELU><<<16384/64, 512, 0, stream>>>(
        bfA + ro * HID, w1t, b1, nullptr, nullptr, nullptr, bfB, FFND, HID);
    rgemm_k<EPI_OUTB | EPI_RESB><<<16384/64, 512, 0, stream>>>(
        bfB, w2t, b2, nullptr, x2b + ro * HID, nullptr, bfA + ro * HID, HID, FFND);
  }
  // bfA = x3 (bf16)

  // fused pool QKV GEMM
  rgemm_k<EPI_OUTB><<<TOK/64, 512, 0, stream>>>(
      bfA, pqkvt, pqkvbias, nullptr, nullptr, nullptr, QKVb, 3*HID, HID);

  // pooling core
  fastattn2_k<true><<<BATCH * NHEAD / 4, 256, 0, stream>>>(
      QKVb, QKVb + HID, QKVb + 2*HID, 3*HID, mask, nullptr, fusedb, qresb);

  // pool out proj (+qres) -> preln f32  (tiny: LDS-staged kernel)
  gemm_k<EPI_OUTF | EPI_RESF><<<dim3(HID/128, BATCH/128), 256, 0, stream>>>(
      fusedb, pwot, pbo, qresb, nullptr, preln, nullptr, BATCH, HID, 2*HID);

  // double LN -> pooled bf16
  ln2x_k<<<BATCH, 256, 0, stream>>>(preln, png, pnb, tng, tnb, pooledb);

  // proj -> news f32 (tiny)
  gemm_k<EPI_OUTF><<<dim3(EOUTD/128, BATCH/128), 256, 0, stream>>>(
      pooledb, pjwt, pjb, nullptr, nullptr, news, nullptr, BATCH, EOUTD, HID);

  // final LN
  lnf_k<<<BATCH, 256, 0, stream>>>(news, ong, onb, out);
}

// Round 5
// 2190.263 us; speedup vs baseline: 2.6927x; 2.6927x over previous
//
#include <hip/hip_runtime.h>
#include <math.h>

// ---------------- configuration ----------------
#define NHEAD 8
#define HID   768
#define FFND  3072
#define EOUTD 256
#define BATCH 1024
#define TOK   (BATCH*64)   // 65536

#define EPI_RESF  1
#define EPI_RESB  2
#define EPI_GELU  4
#define EPI_OUTF  8
#define EPI_OUTB  16

typedef __attribute__((ext_vector_type(8))) short short8;   // 8 x bf16
typedef __attribute__((ext_vector_type(4))) float f32x4;    // MFMA C/D

#define AS1 __attribute__((address_space(1)))
#define AS3 __attribute__((address_space(3)))

__device__ __forceinline__ void async16(const void* g, void* l) {
  __builtin_amdgcn_global_load_lds(
      (AS1 unsigned int*)(unsigned long long)g,
      (AS3 unsigned int*)(unsigned int)(unsigned long long)l,
      16, 0, 0);
}

__device__ __forceinline__ float bf2f(unsigned short u) {
  union { unsigned int i; float f; } c; c.i = ((unsigned int)u) << 16; return c.f;
}
__device__ __forceinline__ unsigned short f2bf(float f) {
  union { float f; unsigned int i; } c; c.f = f;
  unsigned int x = c.i + 0x7fffu + ((c.i >> 16) & 1u);   // RNE
  return (unsigned short)(x >> 16);
}
__device__ __forceinline__ float wsum(float v) {
#pragma unroll
  for (int o = 32; o > 0; o >>= 1) v += __shfl_xor(v, o);
  return v;
}
// GELU with fast erf (Abramowitz-Stegun 7.1.26, |err| < 1.5e-7)
__device__ __forceinline__ float gelu_f(float v) {
  const float z = fabsf(v) * 0.70710678118654752f;
  const float t = 1.0f / (1.0f + 0.3275911f * z);
  const float poly = t * (0.254829592f + t * (-0.284496736f +
                     t * (1.421413741f + t * (-1.453152027f + t * 1.061405429f))));
  float erfv = 1.0f - poly * __expf(-z * z);
  erfv = (v < 0.f) ? -erfv : erfv;
  return 0.5f * v * (1.0f + erfv);
}

// ---------------- GEMM: C[M,N] = A[M,K] @ Wt[N,K]^T (+bias,+resid,gelu) ----------------
// 128x128 tile, BK=64, global_load_lds width-16 staging, XOR-swizzled k-chunks.
// 1D grid with XCD-aware remap: blockIdx.x & 7 selects the XCD (dispatch is
// round-robin); all n-tiles of one m-panel run on the SAME XCD so the A-panel
// is fetched from HBM once per device, and the weight panel stays L2-resident.
// Serpentine n-order so W panels slightly larger than L2 reuse the LRU tail.
// MFMA operands SWAPPED vs the naive order: D-row dim = first operand's lane
// index, so with (W-frag, A-frag) each lane's f32x4 holds 4 CONSECUTIVE
// N-columns -> vectorized bias/resid loads and 8B/16B C-stores.
template<int EPI>
__global__ __launch_bounds__(256, 3) void gemm_k(
    const unsigned short* __restrict__ A, const unsigned short* __restrict__ Wt,
    const float* __restrict__ bias,
    const float* __restrict__ residF, const unsigned short* __restrict__ residB,
    float* __restrict__ outF, unsigned short* __restrict__ outB,
    int M, int N, int K)
{
  __shared__ unsigned short lA[128 * 64];
  __shared__ unsigned short lB[128 * 64];
  const int tid  = threadIdx.x;

  // XCD-aware tile remap
  const int nT  = N >> 7;
  const int per = gridDim.x >> 3;
  const int tile = (blockIdx.x & 7) * per + (blockIdx.x >> 3);
  int m_idx = tile / nT;
  int n_idx = tile - m_idx * nT;
  if (m_idx & 1) n_idx = nT - 1 - n_idx;
  const int n0 = n_idx * 128;
  const int m0 = m_idx * 128;

  const int lane = tid & 63;
  const int wid  = tid >> 6;
  const int wm   = wid & 1, wn = wid >> 1;
  const int m16  = lane & 15, quad = lane >> 4;

  f32x4 zero = {0.0f, 0.0f, 0.0f, 0.0f};
  f32x4 acc[4][4];
#pragma unroll
  for (int i = 0; i < 4; i++)
#pragma unroll
    for (int j = 0; j < 4; j++) acc[i][j] = zero;

  // LDS slot L (0..1023): row = L>>3, kchunk' = L&7; stored global chunk =
  // kchunk' ^ (row&7)  [bank-spread swizzle]
  long aoff[4], boff[4];
#pragma unroll
  for (int j = 0; j < 4; j++) {
    const int L = tid + j * 256;
    const int row = L >> 3;
    const int kc  = (L & 7) ^ (row & 7);
    aoff[j] = (long)(m0 + row) * K + kc * 8;
    boff[j] = (long)(n0 + row) * K + kc * 8;
  }

  for (int k0 = 0; k0 < K; k0 += 64) {
#pragma unroll
    for (int j = 0; j < 4; j++)
      async16(A + aoff[j] + k0, lA + (size_t)(j * 256 + wid * 64) * 8);
#pragma unroll
    for (int j = 0; j < 4; j++)
      async16(Wt + boff[j] + k0, lB + (size_t)(j * 256 + wid * 64) * 8);
    __syncthreads();
#pragma unroll
    for (int s = 0; s < 2; s++) {
      short8 af[4], bfr[4];
#pragma unroll
      for (int mi = 0; mi < 4; mi++) {
        const int row = wm * 64 + mi * 16 + m16;
        const int kc  = (s * 4 + quad) ^ (row & 7);
        af[mi] = *(const short8*)(lA + row * 64 + kc * 8);
      }
#pragma unroll
      for (int ni = 0; ni < 4; ni++) {
        const int row = wn * 64 + ni * 16 + m16;
        const int kc  = (s * 4 + quad) ^ (row & 7);
        bfr[ni] = *(const short8*)(lB + row * 64 + kc * 8);
      }
#pragma unroll
      for (int mi = 0; mi < 4; mi++)
#pragma unroll
        for (int ni = 0; ni < 4; ni++)   // operands swapped: rows of D = W side
          acc[mi][ni] = __builtin_amdgcn_mfma_f32_16x16x32_bf16(bfr[ni], af[mi], acc[mi][ni], 0, 0, 0);
    }
    __syncthreads();
  }

  // epilogue: lane holds m = ..+m16 fixed, 4 consecutive n = nb..nb+3
#pragma unroll
  for (int mi = 0; mi < 4; mi++) {
    const int m = m0 + wm * 64 + mi * 16 + m16;
    const long rb = (long)m * N;
#pragma unroll
    for (int ni = 0; ni < 4; ni++) {
      const int nb = n0 + wn * 64 + ni * 16 + quad * 4;
      f32x4 v = acc[mi][ni];
      const f32x4 bi = *(const f32x4*)(bias + nb);
#pragma unroll
      for (int r = 0; r < 4; r++) v[r] += bi[r];
      if (EPI & EPI_RESF) {
        const f32x4 rf = *(const f32x4*)(residF + rb + nb);
#pragma unroll
        for (int r = 0; r < 4; r++) v[r] += rf[r];
      }
      if (EPI & EPI_RESB) {
        const unsigned long long rv = *(const unsigned long long*)(residB + rb + nb);
#pragma unroll
        for (int r = 0; r < 4; r++) v[r] += bf2f((unsigned short)(rv >> (16 * r)));
      }
      if (EPI & EPI_GELU) {
#pragma unroll
        for (int r = 0; r < 4; r++) v[r] = gelu_f(v[r]);
      }
      if (EPI & EPI_OUTF) *(f32x4*)(outF + rb + nb) = v;
      if (EPI & EPI_OUTB) {
        unsigned long long o = 0;
#pragma unroll
        for (int r = 0; r < 4; r++) o |= (unsigned long long)f2bf(v[r]) << (16 * r);
        *(unsigned long long*)(outB + rb + nb) = o;
      }
    }
  }
}

// ---------------- Fastformer attention / pooling: MFMA Gram-matrix version ----------------
template<bool POOL>
__global__ __launch_bounds__(256) void fastattn2_k(
    const unsigned short* __restrict__ Q,
    const unsigned short* __restrict__ Kx,
    const unsigned short* __restrict__ V,
    int ld,
    const int* __restrict__ mask,
    unsigned short* __restrict__ attnO,
    unsigned short* __restrict__ fused,
    float* __restrict__ qres)
{
  const int lane = threadIdx.x & 63;
  const int wid  = threadIdx.x >> 6;
  const int gw   = blockIdx.x * 4 + wid;
  const int b = gw >> 3, h = gw & 7;
  const int c = lane & 15, quad = lane >> 4;
  const unsigned short* Qp = Q  + (long)b * 64 * ld + h * 96;
  const unsigned short* Kp = Kx + (long)b * 64 * ld + h * 96;
  const unsigned short* Vp = V  + (long)b * 64 * ld + h * 96;
  const float mval = (mask[b * 64 + lane] != 0) ? 1.0f : 0.0f;

  f32x4 G[4][4];
  f32x4 zero = {0.f, 0.f, 0.f, 0.f};
#pragma unroll
  for (int mi = 0; mi < 4; mi++)
#pragma unroll
    for (int ni = 0; ni < 4; ni++) G[mi][ni] = zero;
  float ql[4] = {0.f, 0.f, 0.f, 0.f};

#pragma unroll
  for (int kc = 0; kc < 3; kc++) {
    const int dcol = kc * 32 + quad * 8;
    short8 afr[4], bfr[4];
#pragma unroll
    for (int mi = 0; mi < 4; mi++)
      afr[mi] = *(const short8*)(Kp + (long)(mi * 16 + c) * ld + dcol);
#pragma unroll
    for (int ni = 0; ni < 4; ni++)
      bfr[ni] = *(const short8*)(Qp + (long)(ni * 16 + c) * ld + dcol);
#pragma unroll
    for (int ni = 0; ni < 4; ni++) {
      float t = 0.f;
#pragma unroll
      for (int j = 0; j < 8; j++) t += bf2f((unsigned short)bfr[ni][j]);
      ql[ni] += t;
    }
#pragma unroll
    for (int mi = 0; mi < 4; mi++)
#pragma unroll
      for (int ni = 0; ni < 4; ni++)
        G[mi][ni] = __builtin_amdgcn_mfma_f32_16x16x32_bf16(afr[mi], bfr[ni], G[mi][ni], 0, 0, 0);
  }
#pragma unroll
  for (int ni = 0; ni < 4; ni++) {
    ql[ni] += __shfl_xor(ql[ni], 16);
    ql[ni] += __shfl_xor(ql[ni], 32);
  }

  float qw[4];
  {
    float lg[4], mx = -3.4e38f;
#pragma unroll
    for (int ni = 0; ni < 4; ni++) {
      const float mk = __shfl(mval, ni * 16 + c);
      lg[ni] = (mk > 0.5f) ? ql[ni] * 0.102062072615966f : -10000.0f;
      mx = fmaxf(mx, lg[ni]);
    }
#pragma unroll
    for (int o = 1; o <= 8; o <<= 1) mx = fmaxf(mx, __shfl_xor(mx, o));
    float se = 0.f;
#pragma unroll
    for (int ni = 0; ni < 4; ni++) { qw[ni] = expf(lg[ni] - mx); se += qw[ni]; }
#pragma unroll
    for (int o = 1; o <= 8; o <<= 1) se += __shfl_xor(se, o);
    const float inv = 1.0f / se;
#pragma unroll
    for (int ni = 0; ni < 4; ni++) qw[ni] *= inv;
  }

  float kw[16];
#pragma unroll
  for (int mi = 0; mi < 4; mi++)
#pragma unroll
    for (int r = 0; r < 4; r++) {
      float a = 0.f;
#pragma unroll
      for (int ni = 0; ni < 4; ni++) a += G[mi][ni][r] * qw[ni];
      kw[mi * 4 + r] = a;
    }
#pragma unroll
  for (int i = 0; i < 16; i++)
#pragma unroll
    for (int o = 1; o <= 8; o <<= 1) kw[i] += __shfl_xor(kw[i], o);

  {
    float mx2 = -3.4e38f;
#pragma unroll
    for (int i = 0; i < 16; i++) {
      const int mi = i >> 2, r = i & 3;
      const float mk = __shfl(mval, mi * 16 + quad * 4 + r);
      kw[i] = (mk > 0.5f) ? kw[i] : -10000.0f;
      mx2 = fmaxf(mx2, kw[i]);
    }
    mx2 = fmaxf(mx2, __shfl_xor(mx2, 16));
    mx2 = fmaxf(mx2, __shfl_xor(mx2, 32));
    float se2 = 0.f;
#pragma unroll
    for (int i = 0; i < 16; i++) { kw[i] = expf(kw[i] - mx2); se2 += kw[i]; }
    se2 += __shfl_xor(se2, 16);
    se2 += __shfl_xor(se2, 32);
    const float inv = 1.0f / se2;
#pragma unroll
    for (int i = 0; i < 16; i++) kw[i] *= inv;
  }

  float vw[4];
  {
    float vl[4] = {0.f, 0.f, 0.f, 0.f};
#pragma unroll
    for (int ni = 0; ni < 4; ni++) {
#pragma unroll
      for (int mi = 0; mi < 4; mi++)
#pragma unroll
        for (int r = 0; r < 4; r++) vl[ni] += G[mi][ni][r] * kw[mi * 4 + r];
      vl[ni] += __shfl_xor(vl[ni], 16);
      vl[ni] += __shfl_xor(vl[ni], 32);
    }
    float mx = -3.4e38f;
#pragma unroll
    for (int ni = 0; ni < 4; ni++) {
      const float mk = __shfl(mval, ni * 16 + c);
      vl[ni] = (mk > 0.5f) ? vl[ni] : -10000.0f;
      mx = fmaxf(mx, vl[ni]);
    }
#pragma unroll
    for (int o = 1; o <= 8; o <<= 1) mx = fmaxf(mx, __shfl_xor(mx, o));
    float se = 0.f;
#pragma unroll
    for (int ni = 0; ni < 4; ni++) { vw[ni] = expf(vl[ni] - mx); se += vw[ni]; }
#pragma unroll
    for (int o = 1; o <= 8; o <<= 1) se += __shfl_xor(se, o);
    const float inv = 1.0f / se;
#pragma unroll
    for (int ni = 0; ni < 4; ni++) vw[ni] *= inv;
  }

  if (!POOL) {
    __shared__ float swv[4][64];
    if (quad == 0) {
#pragma unroll
      for (int ni = 0; ni < 4; ni++) swv[wid][ni * 16 + c] = vw[ni];
    }
    __syncthreads();
    unsigned short* Op = attnO + (long)b * 64 * 768 + h * 96;
#pragma unroll
    for (int it = 0; it < 12; it++) {
      const int idx = it * 64 + lane;
      const int s = idx / 12, cw = idx % 12;
      short8 v = *(const short8*)(Vp + (long)s * ld + cw * 8);
      const float w = swv[wid][s];
      short8 o;
#pragma unroll
      for (int j = 0; j < 8; j++) o[j] = (short)f2bf(w * bf2f((unsigned short)v[j]));
      *(short8*)(Op + (long)s * 768 + cw * 8) = o;
    }
  } else {
    float qg[24], vg[24];
#pragma unroll
    for (int kc = 0; kc < 3; kc++) {
      const int dcol = kc * 32 + quad * 8;
      short8 fq[4], fv[4];
#pragma unroll
      for (int ni = 0; ni < 4; ni++) {
        fq[ni] = *(const short8*)(Qp + (long)(ni * 16 + c) * ld + dcol);
        fv[ni] = *(const short8*)(Vp + (long)(ni * 16 + c) * ld + dcol);
      }
#pragma unroll
      for (int j = 0; j < 8; j++) {
        float aq = 0.f, av = 0.f;
#pragma unroll
        for (int ni = 0; ni < 4; ni++) {
          aq += qw[ni] * bf2f((unsigned short)fq[ni][j]);
          av += vw[ni] * bf2f((unsigned short)fv[ni][j]);
        }
        qg[kc * 8 + j] = aq; vg[kc * 8 + j] = av;
      }
    }
#pragma unroll
    for (int i = 0; i < 24; i++) {
#pragma unroll
      for (int o = 1; o <= 8; o <<= 1) {
        qg[i] += __shfl_xor(qg[i], o);
        vg[i] += __shfl_xor(vg[i], o);
      }
    }
    if (c == 0) {
#pragma unroll
      for (int kc = 0; kc < 3; kc++)
#pragma unroll
        for (int j = 0; j < 8; j++) {
          const int d = kc * 32 + quad * 8 + j;
          const float qv = qg[kc * 8 + j], vv = vg[kc * 8 + j];
          fused[(long)b * 1536 + d * 8 + h]        = f2bf(qv);
          fused[(long)b * 1536 + (96 + d) * 8 + h] = f2bf(vv);
          qres[(long)b * 768 + d * 8 + h] = qv;
        }
    }
  }
}

// ---------------- LayerNorms ----------------
__global__ __launch_bounds__(256) void ln768_k(
    const float* __restrict__ x, const float* __restrict__ g, const float* __restrict__ b,
    unsigned short* __restrict__ out)
{
  const int tid = threadIdx.x;
  const long row = blockIdx.x;
  const float* xr = x + row * 768;
  const float v0 = xr[tid], v1 = xr[tid + 256], v2 = xr[tid + 512];
  __shared__ float red[4];
  const int wid = tid >> 6, ln = tid & 63;
  float s = wsum(v0 + v1 + v2);
  if (ln == 0) red[wid] = s;
  __syncthreads();
  const float mean = (red[0] + red[1] + red[2] + red[3]) * (1.0f / 768.0f);
  __syncthreads();
  const float d0 = v0 - mean, d1 = v1 - mean, d2 = v2 - mean;
  float q = wsum(d0 * d0 + d1 * d1 + d2 * d2);
  if (ln == 0) red[wid] = q;
  __syncthreads();
  const float var = (red[0] + red[1] + red[2] + red[3]) * (1.0f / 768.0f);
  const float rs = rsqrtf(var + 1e-5f);
  unsigned short* o = out + row * 768;
  o[tid]       = f2bf(d0 * rs * g[tid]       + b[tid]);
  o[tid + 256] = f2bf(d1 * rs * g[tid + 256] + b[tid + 256]);
  o[tid + 512] = f2bf(d2 * rs * g[tid + 512] + b[tid + 512]);
}

__global__ __launch_bounds__(256) void ln768b_k(
    const unsigned short* __restrict__ x, const float* __restrict__ g, const float* __restrict__ b,
    unsigned short* __restrict__ out)
{
  const int tid = threadIdx.x;
  const long row = blockIdx.x;
  const unsigned short* xr = x + row * 768;
  const float v0 = bf2f(xr[tid]), v1 = bf2f(xr[tid + 256]), v2 = bf2f(xr[tid + 512]);
  __shared__ float red[4];
  const int wid = tid >> 6, ln = tid & 63;
  float s = wsum(v0 + v1 + v2);
  if (ln == 0) red[wid] = s;
  __syncthreads();
  const float mean = (red[0] + red[1] + red[2] + red[3]) * (1.0f / 768.0f);
  __syncthreads();
  const float d0 = v0 - mean, d1 = v1 - mean, d2 = v2 - mean;
  float q = wsum(d0 * d0 + d1 * d1 + d2 * d2);
  if (ln == 0) red[wid] = q;
  __syncthreads();
  const float var = (red[0] + red[1] + red[2] + red[3]) * (1.0f / 768.0f);
  const float rs = rsqrtf(var + 1e-5f);
  unsigned short* o = out + row * 768;
  o[tid]       = f2bf(d0 * rs * g[tid]       + b[tid]);
  o[tid + 256] = f2bf(d1 * rs * g[tid + 256] + b[tid + 256]);
  o[tid + 512] = f2bf(d2 * rs * g[tid + 512] + b[tid + 512]);
}

__global__ __launch_bounds__(256) void ln2x_k(
    const float* __restrict__ x,
    const float* __restrict__ g1, const float* __restrict__ b1,
    const float* __restrict__ g2, const float* __restrict__ b2,
    unsigned short* __restrict__ out)
{
  const int tid = threadIdx.x;
  const long row = blockIdx.x;
  const float* xr = x + row * 768;
  const float v0 = xr[tid], v1 = xr[tid + 256], v2 = xr[tid + 512];
  __shared__ float red[4];
  const int wid = tid >> 6, ln = tid & 63;
  float s = wsum(v0 + v1 + v2);
  if (ln == 0) red[wid] = s;
  __syncthreads();
  const float mean = (red[0] + red[1] + red[2] + red[3]) * (1.0f / 768.0f);
  __syncthreads();
  const float d0 = v0 - mean, d1 = v1 - mean, d2 = v2 - mean;
  float q = wsum(d0 * d0 + d1 * d1 + d2 * d2);
  if (ln == 0) red[wid] = q;
  __syncthreads();
  const float var = (red[0] + red[1] + red[2] + red[3]) * (1.0f / 768.0f);
  const float rs = rsqrtf(var + 1e-5f);
  const float y0 = d0 * rs * g1[tid]       + b1[tid];
  const float y1 = d1 * rs * g1[tid + 256] + b1[tid + 256];
  const float y2 = d2 * rs * g1[tid + 512] + b1[tid + 512];
  __syncthreads();
  float s2 = wsum(y0 + y1 + y2);
  if (ln == 0) red[wid] = s2;
  __syncthreads();
  const float mean2 = (red[0] + red[1] + red[2] + red[3]) * (1.0f / 768.0f);
  __syncthreads();
  const float e0 = y0 - mean2, e1 = y1 - mean2, e2 = y2 - mean2;
  float q2 = wsum(e0 * e0 + e1 * e1 + e2 * e2);
  if (ln == 0) red[wid] = q2;
  __syncthreads();
  const float var2 = (red[0] + red[1] + red[2] + red[3]) * (1.0f / 768.0f);
  const float rs2 = rsqrtf(var2 + 1e-5f);
  unsigned short* o = out + row * 768;
  o[tid]       = f2bf(e0 * rs2 * g2[tid]       + b2[tid]);
  o[tid + 256] = f2bf(e1 * rs2 * g2[tid + 256] + b2[tid + 256]);
  o[tid + 512] = f2bf(e2 * rs2 * g2[tid + 512] + b2[tid + 512]);
}

__global__ __launch_bounds__(256) void lnf_k(
    const float* __restrict__ x, const float* __restrict__ g, const float* __restrict__ b,
    float* __restrict__ out)
{
  const int tid = threadIdx.x;
  const long row = blockIdx.x;
  const float v = x[row * 256 + tid];
  __shared__ float red[4];
  const int wid = tid >> 6, ln = tid & 63;
  float s = wsum(v);
  if (ln == 0) red[wid] = s;
  __syncthreads();
  const float mean = (red[0] + red[1] + red[2] + red[3]) * (1.0f / 256.0f);
  __syncthreads();
  const float d = v - mean;
  float q = wsum(d * d);
  if (ln == 0) red[wid] = q;
  __syncthreads();
  const float var = (red[0] + red[1] + red[2] + red[3]) * (1.0f / 256.0f);
  const float rs = rsqrtf(var + 1e-5f);
  out[row * 256 + tid] = d * rs * g[tid] + b[tid];
}

// ---------------- weight transpose + cast, bias concat ----------------
__global__ __launch_bounds__(256) void tcast_k(
    const float* __restrict__ W, unsigned short* __restrict__ Wt, int K, int N)
{
  __shared__ float t[32][33];
  const int tx = threadIdx.x & 31, ty = threadIdx.x >> 5;
  const int n0 = blockIdx.x * 32, k0 = blockIdx.y * 32;
#pragma unroll
  for (int j = 0; j < 32; j += 8)
    t[ty + j][tx] = W[(long)(k0 + ty + j) * N + n0 + tx];
  __syncthreads();
#pragma unroll
  for (int j = 0; j < 32; j += 8)
    Wt[(long)(n0 + ty + j) * K + k0 + tx] = f2bf(t[tx][ty + j]);
}

__global__ __launch_bounds__(256) void cat3_k(
    const float* __restrict__ a, const float* __restrict__ b, const float* __restrict__ c,
    float* __restrict__ dst)
{
  const int i = blockIdx.x * 256 + threadIdx.x;   // grid 9 -> 2304
  dst[i] = (i < 768) ? a[i] : (i < 1536 ? b[i - 768] : c[i - 1536]);
}

// ---------------- launcher ----------------
extern "C" void kernel_launch(void* const* d_in, const int* in_sizes, int n_in,
                              void* d_out, int out_size, void* d_ws, size_t ws_size,
                              hipStream_t stream)
{
  const float* x    = (const float*)d_in[0];
  const int*   mask = (const int*)d_in[1];
  const float* n1g = (const float*)d_in[2];  const float* n1b = (const float*)d_in[3];
  const float* wq  = (const float*)d_in[4];  const float* bq  = (const float*)d_in[5];
  const float* wk  = (const float*)d_in[6];  const float* bk  = (const float*)d_in[7];
  const float* wv  = (const float*)d_in[8];  const float* bv  = (const float*)d_in[9];
  const float* wo  = (const float*)d_in[10]; const float* bo  = (const float*)d_in[11];
  const float* n2g = (const float*)d_in[12]; const float* n2b = (const float*)d_in[13];
  const float* w1  = (const float*)d_in[14]; const float* b1  = (const float*)d_in[15];
  const float* w2  = (const float*)d_in[16]; const float* b2  = (const float*)d_in[17];
  const float* pwq = (const float*)d_in[18]; const float* pbq = (const float*)d_in[19];
  const float* pwk = (const float*)d_in[20]; const float* pbk = (const float*)d_in[21];
  const float* pwv = (const float*)d_in[22]; const float* pbv = (const float*)d_in[23];
  const float* pwo = (const float*)d_in[24]; const float* pbo = (const float*)d_in[25];
  const float* png = (const float*)d_in[26]; const float* pnb = (const float*)d_in[27];
  const float* tng = (const float*)d_in[28]; const float* tnb = (const float*)d_in[29];
  const float* pjw = (const float*)d_in[30]; const float* pjb = (const float*)d_in[31];
  const float* ong = (const float*)d_in[32]; const float* onb = (const float*)d_in[33];
  float* out = (float*)d_out;

  char* p = (char*)d_ws;
  auto alloc = [&](size_t n) { void* r = (void*)p; p += (n + 255) & ~(size_t)255; return r; };

  unsigned short* wqkvt = (unsigned short*)alloc((size_t)3 * HID * HID * 2);  // 2304 x 768
  unsigned short* wot   = (unsigned short*)alloc((size_t)HID * HID * 2);
  unsigned short* w1t   = (unsigned short*)alloc((size_t)FFND * HID * 2);
  unsigned short* w2t   = (unsigned short*)alloc((size_t)HID * FFND * 2);
  unsigned short* pqkvt = (unsigned short*)alloc((size_t)3 * HID * HID * 2);
  unsigned short* pwot  = (unsigned short*)alloc((size_t)HID * 2 * HID * 2);
  unsigned short* pjwt  = (unsigned short*)alloc((size_t)EOUTD * HID * 2);
  float*          qkvbias = (float*)alloc((size_t)3 * HID * 4);
  float*          pqkvbias= (float*)alloc((size_t)3 * HID * 4);
  unsigned short* bfA   = (unsigned short*)alloc((size_t)TOK * HID * 2);      // h1 -> h -> x3
  unsigned short* QKVb  = (unsigned short*)alloc((size_t)TOK * 3 * HID * 2);  // 65536 x 2304
  unsigned short* bfB   = (unsigned short*)alloc((size_t)TOK * HID * 2);      // attn -> ffn-hidden chunk
  unsigned short* x2b   = (unsigned short*)alloc((size_t)TOK * HID * 2);      // x2 (bf16)
  unsigned short* fusedb= (unsigned short*)alloc((size_t)BATCH * 2 * HID * 2);
  float*          qresb = (float*)alloc((size_t)BATCH * HID * 4);
  float*          preln = (float*)alloc((size_t)BATCH * HID * 4);
  unsigned short* pooledb=(unsigned short*)alloc((size_t)BATCH * HID * 2);
  float*          news  = (float*)alloc((size_t)BATCH * EOUTD * 4);
  (void)ws_size; (void)in_sizes; (void)n_in; (void)out_size;

  // weight prep
  tcast_k<<<dim3(HID/32,  HID/32),  256, 0, stream>>>(wq,  wqkvt,                 HID, HID);
  tcast_k<<<dim3(HID/32,  HID/32),  256, 0, stream>>>(wk,  wqkvt + (size_t)HID*HID,   HID, HID);
  tcast_k<<<dim3(HID/32,  HID/32),  256, 0, stream>>>(wv,  wqkvt + (size_t)2*HID*HID, HID, HID);
  tcast_k<<<dim3(HID/32,  HID/32),  256, 0, stream>>>(wo,  wot,  HID,  HID);
  tcast_k<<<dim3(FFND/32, HID/32),  256, 0, stream>>>(w1,  w1t,  HID,  FFND);
  tcast_k<<<dim3(HID/32,  FFND/32), 256, 0, stream>>>(w2,  w2t,  FFND, HID);
  tcast_k<<<dim3(HID/32,  HID/32),  256, 0, stream>>>(pwq, pqkvt,                 HID, HID);
  tcast_k<<<dim3(HID/32,  HID/32),  256, 0, stream>>>(pwk, pqkvt + (size_t)HID*HID,   HID, HID);
  tcast_k<<<dim3(HID/32,  HID/32),  256, 0, stream>>>(pwv, pqkvt + (size_t)2*HID*HID, HID, HID);
  tcast_k<<<dim3(HID/32,  (2*HID)/32), 256, 0, stream>>>(pwo, pwot, 2*HID, HID);
  tcast_k<<<dim3(EOUTD/32, HID/32), 256, 0, stream>>>(pjw, pjwt, HID,  EOUTD);
  cat3_k<<<9, 256, 0, stream>>>(bq,  bk,  bv,  qkvbias);
  cat3_k<<<9, 256, 0, stream>>>(pbq, pbk, pbv, pqkvbias);

  // LN1
  ln768_k<<<TOK, 256, 0, stream>>>(x, n1g, n1b, bfA);

  // fused QKV GEMM: 65536 x 2304, K=768
  gemm_k<EPI_OUTB><<<(TOK/128)*(3*HID/128), 256, 0, stream>>>(
      bfA, wqkvt, qkvbias, nullptr, nullptr, nullptr, QKVb, TOK, 3*HID, HID);

  // fastformer attention -> bfB (stride 768)
  fastattn2_k<false><<<BATCH * NHEAD / 4, 256, 0, stream>>>(
      QKVb, QKVb + HID, QKVb + 2*HID, 3*HID, mask, bfB, nullptr, nullptr);

  // wo proj + f32 resid x -> x2 (bf16)
  gemm_k<EPI_OUTB | EPI_RESF><<<(TOK/128)*(HID/128), 256, 0, stream>>>(
      bfB, wot, bo, x, nullptr, nullptr, x2b, TOK, HID, HID);

  // LN2 (bf16 in)
  ln768b_k<<<TOK, 256, 0, stream>>>(x2b, n2g, n2b, bfA);

  // FFN in 4 row-chunks of 16384 (hidden reuses bfB)
  for (int c = 0; c < 4; c++) {
    const size_t ro = (size_t)c * 16384;
    gemm_k<EPI_OUTB | EPI_GELU><<<(16384/128)*(FFND/128), 256, 0, stream>>>(
        bfA + ro * HID, w1t, b1, nullptr, nullptr, nullptr, bfB, 16384, FFND, HID);
    gemm_k<EPI_OUTB | EPI_RESB><<<(16384/128)*(HID/128), 256, 0, stream>>>(
        bfB, w2t, b2, nullptr, x2b + ro * HID, nullptr, bfA + ro * HID, 16384, HID, FFND);
  }
  // bfA = x3 (bf16)

  // fused pool QKV GEMM
  gemm_k<EPI_OUTB><<<(TOK/128)*(3*HID/128), 256, 0, stream>>>(
      bfA, pqkvt, pqkvbias, nullptr, nullptr, nullptr, QKVb, TOK, 3*HID, HID);

  // pooling core
  fastattn2_k<true><<<BATCH * NHEAD / 4, 256, 0, stream>>>(
      QKVb, QKVb + HID, QKVb + 2*HID, 3*HID, mask, nullptr, fusedb, qresb);

  // pool out proj (+qres) -> preln f32
  gemm_k<EPI_OUTF | EPI_RESF><<<(BATCH/128)*(HID/128), 256, 0, stream>>>(
      fusedb, pwot, pbo, qresb, nullptr, preln, nullptr, BATCH, HID, 2*HID);

  // double LN -> pooled bf16
  ln2x_k<<<BATCH, 256, 0, stream>>>(preln, png, pnb, tng, tnb, pooledb);

  // proj -> news f32
  gemm_k<EPI_OUTF><<<(BATCH/128)*(EOUTD/128), 256, 0, stream>>>(
      pooledb, pjwt, pjb, nullptr, nullptr, news, nullptr, BATCH, EOUTD, HID);

  // final LN
  lnf_k<<<BATCH, 256, 0, stream>>>(news, ong, onb, out);
}